// Round 3
// baseline (584.915 us; speedup 1.0000x reference)
//
#include <hip/hip_runtime.h>

#define D 64
#define KCODES 512
#define KT 8
#define BLOCK 256
// N = 131072 rows; 512 blocks x 256 threads; 1 thread = 1 row, 8 codes in flight.

// cc[k] = ||codebook_k||^2 into d_ws (re-poisoned every launch; recompute).
// Same fma order as verified round-1 kernel.
__global__ void __launch_bounds__(256) vq_cc_kernel(const float* __restrict__ cb,
                                                    float* __restrict__ cc) {
    int k = blockIdx.x * 256 + threadIdx.x;
    if (k < KCODES) {
        float s = 0.f;
        #pragma unroll
        for (int d = 0; d < D; ++d) s = fmaf(cb[k * D + d], cb[k * D + d], s);
        cc[k] = s;
    }
}

__global__ __launch_bounds__(BLOCK, 2) void vq_kernel(const float* __restrict__ x,
                                                      const float* __restrict__ cb,
                                                      const float* __restrict__ cc,
                                                      float* __restrict__ out) {
    // 64 KB x-tile, XOR-swizzled so row-reads and staging-writes are both
    // conflict-free. Reused as s_bi[] after the k-loop (64 KB LDS/block cap).
    __shared__ float4 s_x[BLOCK * 16];
    const int t = threadIdx.x;

    // Stage x tile (256 rows x 64 floats), coalesced global float4 reads.
    const float4* xg = (const float4*)x + (size_t)blockIdx.x * (BLOCK * 16);
    #pragma unroll
    for (int j = 0; j < 16; ++j) {
        const int f4 = j * BLOCK + t;
        const int r  = f4 >> 4;     // row within block
        const int db = f4 & 15;     // d-block (float4) within row
        s_x[r * 16 + (db ^ (r & 15))] = xg[f4];
    }
    __syncthreads();

    // xx = ||x_row||^2 : d ascending, single accumulator (round-1 exact order)
    float xx = 0.f;
    #pragma unroll
    for (int db = 0; db < 16; ++db) {
        const float4 q = s_x[t * 16 + (db ^ (t & 15))];
        xx = fmaf(q.x, q.x, xx);
        xx = fmaf(q.y, q.y, xx);
        xx = fmaf(q.z, q.z, xx);
        xx = fmaf(q.w, q.w, xx);
    }

    const float4* cbv = (const float4*)cb;
    float best = __builtin_inff();
    int bi = 0;

    for (int kt = 0; kt < KCODES / KT; ++kt) {
        // even-d / odd-d accumulator pairs per code: identical chains to round 1
        float dot0[KT], dot1[KT];
        #pragma unroll
        for (int kk = 0; kk < KT; ++kk) { dot0[kk] = 0.f; dot1[kk] = 0.f; }

        #pragma unroll 4
        for (int db = 0; db < 16; ++db) {
            const float4 q = s_x[t * 16 + (db ^ (t & 15))];  // 1 ds_read_b128 -> 32 FMA
            #pragma unroll
            for (int kk = 0; kk < KT; ++kk) {
                // wave-uniform address -> s_load; SGPR operand is free in v_fma
                const float4 c = cbv[(kt * KT + kk) * 16 + db];
                dot0[kk] = fmaf(q.x, c.x, dot0[kk]);
                dot1[kk] = fmaf(q.y, c.y, dot1[kk]);
                dot0[kk] = fmaf(q.z, c.z, dot0[kk]);
                dot1[kk] = fmaf(q.w, c.w, dot1[kk]);
            }
        }
        #pragma unroll
        for (int kk = 0; kk < KT; ++kk) {
            const int k = kt * KT + kk;
            const float dist = (xx - 2.f * (dot0[kk] + dot1[kk])) + cc[k];
            if (dist < best) { best = dist; bi = k; }   // strict < = first-occurrence
        }
    }

    __syncthreads();                  // all lanes done reading s_x
    int* s_bi = (int*)s_x;            // alias: stay under 64 KB LDS/block
    s_bi[t] = bi;
    __syncthreads();

    // Coalesced gather+store (round-2 verified epilogue): WRITE_SIZE == output.
    float4* outv = (float4*)out + (size_t)blockIdx.x * (BLOCK * 16);
    #pragma unroll
    for (int j = 0; j < 16; ++j) {
        const int f4 = j * BLOCK + t;
        const int r  = f4 >> 4;
        const int q  = f4 & 15;
        outv[f4] = cbv[s_bi[r] * 16 + q];
    }
}

extern "C" void kernel_launch(void* const* d_in, const int* in_sizes, int n_in,
                              void* d_out, int out_size, void* d_ws, size_t ws_size,
                              hipStream_t stream) {
    const float* x  = (const float*)d_in[0];   // 131072 x 64
    const float* cb = (const float*)d_in[1];   // 512 x 64
    float* out = (float*)d_out;
    float* cc  = (float*)d_ws;                 // 512 floats

    vq_cc_kernel<<<2, 256, 0, stream>>>(cb, cc);

    const int N = in_sizes[0] / D;             // 131072
    vq_kernel<<<N / BLOCK, BLOCK, 0, stream>>>(x, cb, cc, out);
}

// Round 4
// 196.215 us; speedup vs baseline: 2.9810x; 2.9810x over previous
//
#include <hip/hip_runtime.h>

#define D 64
#define KCODES 512
#define BLOCK 256
#define CHUNK 128          // codes staged in LDS at a time
#define CBPAD 72           // 64 + 8 bf16 pad -> conflict-minimal ds_read_b128

typedef short short8 __attribute__((ext_vector_type(8)));
typedef float f32x4  __attribute__((ext_vector_type(4)));

// fp32 -> bf16 RNE (hi), plus bf16 of the remainder (lo). x ~ N(0,1): no NaN/inf.
__device__ __forceinline__ void bf16_split(float f, unsigned short& h, unsigned short& l) {
    union { float f; unsigned u; } a; a.f = f;
    unsigned r = a.u + 0x7FFFu + ((a.u >> 16) & 1u);
    h = (unsigned short)(r >> 16);
    union { unsigned u; float f; } b; b.u = (unsigned)h << 16;
    float rem = f - b.f;
    union { float f; unsigned u; } c; c.f = rem;
    unsigned r2 = c.u + 0x7FFFu + ((c.u >> 16) & 1u);
    l = (unsigned short)(r2 >> 16);
}

__global__ __launch_bounds__(BLOCK, 2) void vq_mfma(const float* __restrict__ x,
                                                    const float* __restrict__ cb,
                                                    float* __restrict__ out) {
    __shared__ unsigned short s_cbh[CHUNK * CBPAD];  // 18 KB
    __shared__ unsigned short s_cbl[CHUNK * CBPAD];  // 18 KB
    __shared__ float s_cc[KCODES];                   // 2 KB
    __shared__ float s_xx[BLOCK];                    // 1 KB
    __shared__ int   s_bi[BLOCK];                    // 1 KB
    __shared__ int   s_flag[BLOCK];                  // 1 KB
    __shared__ int   s_nflag;

    const int t    = threadIdx.x;
    const int w    = t >> 6;        // wave 0..3
    const int lane = t & 63;
    const int quad = lane >> 4;
    const int col  = lane & 15;
    const float4* xv4  = (const float4*)x;
    const float4* cbv4 = (const float4*)cb;

    if (t == 0) s_nflag = 0;

    // cc[k] = ||c_k||^2, round-1 fma order (d ascending, one accumulator)
    #pragma unroll
    for (int i = 0; i < 2; ++i) {
        const int k = t + 256 * i;
        float s = 0.f;
        for (int db = 0; db < 16; ++db) {
            float4 q = cbv4[k * 16 + db];
            s = fmaf(q.x, q.x, s); s = fmaf(q.y, q.y, s);
            s = fmaf(q.z, q.z, s); s = fmaf(q.w, q.w, s);
        }
        s_cc[k] = s;
    }
    // xx for this block's 256 rows, round-1 order
    {
        const size_t gr = (size_t)blockIdx.x * BLOCK + t;
        float s = 0.f;
        for (int db = 0; db < 16; ++db) {
            float4 q = xv4[gr * 16 + db];
            s = fmaf(q.x, q.x, s); s = fmaf(q.y, q.y, s);
            s = fmaf(q.z, q.z, s); s = fmaf(q.w, q.w, s);
        }
        s_xx[t] = s;
    }

    // x fragments: wave w owns rows w*64 .. w*64+63 = 4 row-tiles of 16.
    // A-layout (m97-verified, A.B^T): m = lane&15, k = quad*8 + j.
    short8 xh[4][2], xl[4][2];
    const size_t growb = (size_t)blockIdx.x * BLOCK + w * 64;
    #pragma unroll
    for (int rt = 0; rt < 4; ++rt) {
        const size_t row = growb + rt * 16 + col;
        #pragma unroll
        for (int kt = 0; kt < 2; ++kt) {
            float4 p0 = xv4[row * 16 + kt * 8 + quad * 2];
            float4 p1 = xv4[row * 16 + kt * 8 + quad * 2 + 1];
            float v[8] = {p0.x, p0.y, p0.z, p0.w, p1.x, p1.y, p1.z, p1.w};
            short8 hh, ll;
            #pragma unroll
            for (int j = 0; j < 8; ++j) {
                unsigned short h, l;
                bf16_split(v[j], h, l);
                hh[j] = (short)h; ll[j] = (short)l;
            }
            xh[rt][kt] = hh; xl[rt][kt] = ll;
        }
    }

    __syncthreads();   // s_xx / s_cc visible to all waves

    // per-lane xx for the C/D rows it will hold: row = quad*4 + r (m89 layout)
    float xxr[16];
    #pragma unroll
    for (int rt = 0; rt < 4; ++rt)
        #pragma unroll
        for (int r = 0; r < 4; ++r)
            xxr[rt * 4 + r] = s_xx[w * 64 + rt * 16 + quad * 4 + r];

    float best[16], second[16]; int bis[16];
    #pragma unroll
    for (int i = 0; i < 16; ++i) { best[i] = __builtin_inff(); second[i] = __builtin_inff(); bis[i] = 0; }

    for (int c = 0; c < KCODES / CHUNK; ++c) {
        __syncthreads();   // previous chunk fully consumed
        // stage chunk: 8192 fp32, coalesced; per wave each i covers one code row
        #pragma unroll
        for (int i = 0; i < 32; ++i) {
            const int e  = i * 256 + t;
            const int lc = e >> 6, d = e & 63;
            unsigned short h, l;
            bf16_split(cb[c * (CHUNK * D) + e], h, l);
            s_cbh[lc * CBPAD + d] = h;
            s_cbl[lc * CBPAD + d] = l;
        }
        __syncthreads();

        for (int ct = 0; ct < CHUNK / 16; ++ct) {
            const int lc = ct * 16 + col;            // B-layout: n = lane&15
            short8 ch0 = *(const short8*)&s_cbh[lc * CBPAD + 0  + quad * 8];
            short8 ch1 = *(const short8*)&s_cbh[lc * CBPAD + 32 + quad * 8];
            short8 cl0 = *(const short8*)&s_cbl[lc * CBPAD + 0  + quad * 8];
            short8 cl1 = *(const short8*)&s_cbl[lc * CBPAD + 32 + quad * 8];
            const int   kglob = c * CHUNK + ct * 16 + col;
            const float cck   = s_cc[kglob];

            #pragma unroll
            for (int rt = 0; rt < 4; ++rt) {
                f32x4 acc = {0.f, 0.f, 0.f, 0.f};
                acc = __builtin_amdgcn_mfma_f32_16x16x32_bf16(xh[rt][0], ch0, acc, 0, 0, 0);
                acc = __builtin_amdgcn_mfma_f32_16x16x32_bf16(xh[rt][0], cl0, acc, 0, 0, 0);
                acc = __builtin_amdgcn_mfma_f32_16x16x32_bf16(xl[rt][0], ch0, acc, 0, 0, 0);
                acc = __builtin_amdgcn_mfma_f32_16x16x32_bf16(xl[rt][0], cl0, acc, 0, 0, 0);
                acc = __builtin_amdgcn_mfma_f32_16x16x32_bf16(xh[rt][1], ch1, acc, 0, 0, 0);
                acc = __builtin_amdgcn_mfma_f32_16x16x32_bf16(xh[rt][1], cl1, acc, 0, 0, 0);
                acc = __builtin_amdgcn_mfma_f32_16x16x32_bf16(xl[rt][1], ch1, acc, 0, 0, 0);
                acc = __builtin_amdgcn_mfma_f32_16x16x32_bf16(xl[rt][1], cl1, acc, 0, 0, 0);
                #pragma unroll
                for (int r = 0; r < 4; ++r) {
                    // bit-exact round-1 expression: (xx - 2*dot) + cc
                    const float dist = fmaf(-2.f, acc[r], xxr[rt * 4 + r]) + cck;
                    const int idx = rt * 4 + r;
                    const bool lt = dist < best[idx];
                    second[idx] = fminf(second[idx], fmaxf(best[idx], dist));
                    if (lt) { best[idx] = dist; bis[idx] = kglob; }
                }
            }
        }
    }

    // reduce over the 16 lanes of each quad (they hold different codes, same rows)
    #pragma unroll
    for (int rt = 0; rt < 4; ++rt) {
        #pragma unroll
        for (int r = 0; r < 4; ++r) {
            const int idx = rt * 4 + r;
            float b = best[idx], s2 = second[idx]; int bi = bis[idx];
            #pragma unroll
            for (int off = 1; off < 16; off <<= 1) {
                float ob  = __shfl_xor(b, off);
                int   obi = __shfl_xor(bi, off);
                float os  = __shfl_xor(s2, off);
                s2 = fminf(fminf(s2, os), fmaxf(b, ob));
                if (ob < b || (ob == b && obi < bi)) { b = ob; bi = obi; }
            }
            if (col == 0) {
                const int row = w * 64 + rt * 16 + quad * 4 + r;
                s_bi[row] = bi;
                if (s2 - b < 1e-3f) {               // near-tie: exact recompute below
                    int p = atomicAdd(&s_nflag, 1);
                    s_flag[p] = row;
                }
            }
        }
    }
    __syncthreads();

    // exact fp32 re-argmin for flagged rows (~1 per block): one wave per row.
    const int nf = s_nflag;
    for (int i = w; i < nf; i += 4) {
        const int row = s_flag[i];
        const size_t gr = (size_t)blockIdx.x * BLOCK + row;
        float4 xr4[16];
        #pragma unroll
        for (int db = 0; db < 16; ++db) xr4[db] = xv4[gr * 16 + db];
        const float xxv = s_xx[row];
        float b = __builtin_inff(); int bi = 0;
        for (int kk = 0; kk < 8; ++kk) {
            const int k = lane * 8 + kk;             // ascending within lane
            float dot0 = 0.f, dot1 = 0.f;            // round-1 even/odd order
            #pragma unroll
            for (int db = 0; db < 16; ++db) {
                float4 cq = cbv4[k * 16 + db];
                dot0 = fmaf(xr4[db].x, cq.x, dot0);
                dot1 = fmaf(xr4[db].y, cq.y, dot1);
                dot0 = fmaf(xr4[db].z, cq.z, dot0);
                dot1 = fmaf(xr4[db].w, cq.w, dot1);
            }
            const float dist = (xxv - 2.f * (dot0 + dot1)) + s_cc[k];
            if (dist < b) { b = dist; bi = k; }
        }
        #pragma unroll
        for (int off = 1; off < 64; off <<= 1) {     // lower-index tie-break
            float ob  = __shfl_xor(b, off);
            int   obi = __shfl_xor(bi, off);
            if (ob < b || (ob == b && obi < bi)) { b = ob; bi = obi; }
        }
        if (lane == 0) s_bi[row] = bi;
    }
    __syncthreads();

    // coalesced gather+store (round-2 verified epilogue)
    float4* outv = (float4*)out + (size_t)blockIdx.x * (BLOCK * 16);
    #pragma unroll
    for (int j = 0; j < 16; ++j) {
        const int f4 = j * 256 + t;
        const int r  = f4 >> 4;
        const int q  = f4 & 15;
        outv[f4] = cbv4[s_bi[r] * 16 + q];
    }
}

extern "C" void kernel_launch(void* const* d_in, const int* in_sizes, int n_in,
                              void* d_out, int out_size, void* d_ws, size_t ws_size,
                              hipStream_t stream) {
    const float* x  = (const float*)d_in[0];   // 131072 x 64
    const float* cb = (const float*)d_in[1];   // 512 x 64
    float* out = (float*)d_out;

    const int N = in_sizes[0] / D;             // 131072
    vq_mfma<<<N / BLOCK, BLOCK, 0, stream>>>(x, cb, out);
}